// Round 2
// 103.260 us; speedup vs baseline: 1.0249x; 1.0249x over previous
//
#include <hip/hip_runtime.h>
#include <math.h>

// Problem constants
#define NN   1024
#define PP   4
#define SS   12
#define MM   64
#define KK   16
#define LL   8
#define MKK  80          // M + K
#define NSYM 13          // S + 1

// Output layout (float element offsets in d_out)
#define OFF_PILOT  0
#define OFF_SIG    524288      // N*P*1*M*2
#define OFF_H      6815744     // + N*P*S*M*2
#define OFF_SCALAR 7340032     // + N*P*M*2

#define NOISE_PWR   1.5625e-4f             // PWR/(M*10^(0.1*SNR)) = 1/6400
#define NOISE_SCALE 8.8388347648318447e-3f // sqrt(NOISE_PWR/2)

// ALGEBRAIC IDENTITY used here: CP length (K=16) >= channel length (L=8), so
// the linear convolution restricted to the CP-stripped window of each symbol
// is exactly a 64-pt circular convolution of that symbol's time signal.
// FFT(IFFT(X)) = X  =>  info[s,k] = H64[k]*X[s,k] + NOISE_SCALE*FFT64(noise[s,K:])[k].
// Only the noise FFTs remain; no IFFT, no FIR, no LDS, no barriers.
//
// Issue-rate optimizations vs the 106us baseline (kernel ~22us vs ~13us BW floor):
//  * __shfl_xor (ds_bpermute, LDS pipe) replaced per-stage: DPP quad_perm for
//    xor1/xor2, single ds_swizzle for xor4/8/16, v_permlane32_swap for xor32.
//    permlane32_swap(v,v) yields r[0]=v[lane&31], r[1]=v[lane|32] on EVERY lane
//    (partner = hi ? r[0] : r[1] — the round-1 bug was the inverted select).
//    Stage 5 needs no select at all: v' = fmaf(sg5, r[1], r[0]) on all lanes.
//  * stage twiddles derived from one sincos via tw[s] = -w^(32>>s); the minus
//    sign is folded into the butterfly by applying sgn to the SHUFFLED operand
//    (v' = sgn*other + own_twiddled) instead of the own operand.
//  * NOISE_SCALE folded into tw[0] (FFT is linear) - no pre-scale of inputs.
//  * cof tap scales sqrt(exp(-t/4)/(2*sum)) are compile-time literals.

__device__ __forceinline__ float2 cmul(float2 a, float2 b) {
    return make_float2(a.x*b.x - a.y*b.y, a.x*b.y + a.y*b.x);
}

// lane-xor exchange for masks 1,2,4,8,16: single instruction each
template<int S>
__device__ __forceinline__ float xsh(float v) {
    if constexpr (S == 0) {        // xor 1: DPP quad_perm [1,0,3,2] = 0xB1
        return __int_as_float(__builtin_amdgcn_update_dpp(
            0, __float_as_int(v), 0xB1, 0xF, 0xF, true));
    } else if constexpr (S == 1) { // xor 2: DPP quad_perm [2,3,0,1] = 0x4E
        return __int_as_float(__builtin_amdgcn_update_dpp(
            0, __float_as_int(v), 0x4E, 0xF, 0xF, true));
    } else {                       // xor 4/8/16: ds_swizzle BitMode (xor<<10 | and 0x1F)
        return __int_as_float(__builtin_amdgcn_ds_swizzle(
            __float_as_int(v), ((1 << S) << 10) | 0x1F));
    }
}

// xor-32 exchange via v_permlane32_swap_b32 (VALU, no LDS pipe).
// Returns {lo_half_value, hi_half_value} as seen by every lane.
__device__ __forceinline__ float2 swap32(float v) {
    auto r = __builtin_amdgcn_permlane32_swap(__float_as_int(v), __float_as_int(v),
                                              false, false);
    return make_float2(__int_as_float(r[0]), __int_as_float(r[1]));
}

// One DIT butterfly stage. tw holds the POSITIVE power w^(32>>S) on "up" lanes,
// (1,0) on "down" lanes; sgn = up ? +1 : -1 applied to the shuffled partner:
//   b   = v * tw
//   v'  = sgn * partner(b) + b
// For S==5 (xor 32): partner/own resolve to r[1]/r[0] uniformly:
//   v'  = sgn * r[1] + r[0]        (lo: r0-r1, hi: r0+r1)
template<int S, int NS>
__device__ __forceinline__ void fft_stage(float2* v, float2 tw, float sg) {
    float bx[NS], by[NS];
    #pragma unroll
    for (int j = 0; j < NS; ++j) {
        bx[j] = v[j].x * tw.x - v[j].y * tw.y;
        by[j] = v[j].x * tw.y + v[j].y * tw.x;
    }
    #pragma unroll
    for (int j = 0; j < NS; ++j) {
        if constexpr (S == 5) {
            float2 rx = swap32(bx[j]);
            float2 ry = swap32(by[j]);
            v[j].x = fmaf(sg, rx.y, rx.x);
            v[j].y = fmaf(sg, ry.y, ry.x);
        } else {
            float ox = xsh<S>(bx[j]);
            float oy = xsh<S>(by[j]);
            v[j].x = fmaf(sg, ox, bx[j]);
            v[j].y = fmaf(sg, oy, by[j]);
        }
    }
}

// DIT radix-2 across 64 lanes: bitrev-order in -> natural-order out, forward sign.
template<int NS>
__device__ __forceinline__ void fft64_dit(float2* v, const float2* tw, const float* sgn) {
    fft_stage<0, NS>(v, tw[0], sgn[0]);
    fft_stage<1, NS>(v, tw[1], sgn[1]);
    fft_stage<2, NS>(v, tw[2], sgn[2]);
    fft_stage<3, NS>(v, tw[3], sgn[3]);
    fft_stage<4, NS>(v, tw[4], sgn[4]);
    fft_stage<5, NS>(v, tw[5], sgn[5]);
}

__global__ __launch_bounds__(256) void ofdm_kernel(
    const float2* __restrict__ x,          // (NP, S, M)
    const float2* __restrict__ pilot_raw,  // (NP, M)
    const float2* __restrict__ cof_unit,   // (NP, L)
    const float2* __restrict__ noise_unit, // (NP, NSYM, MKK)
    float2* __restrict__ out_pilot,        // (NP, M)
    float2* __restrict__ out_sig,          // (NP, S, M)
    float2* __restrict__ out_H,            // (NP, M)
    float*  __restrict__ out_scalar)
{
    const int b    = blockIdx.x;
    const int tid  = threadIdx.x;
    const int wid  = tid >> 6;
    const int lane = tid & 63;
    const bool hi  = (lane & 32) != 0;

    const float2* xb = x          + (size_t)b * (SS*MM);
    const float2* pb = pilot_raw  + (size_t)b * MM;
    const float2* cb = cof_unit   + (size_t)b * LL;
    const float2* nb = noise_unit + (size_t)b * (NSYM*MKK);

    const int rb = (int)(__brev((unsigned)lane) >> 26);   // bitrev6(lane)

    // --- channel taps (block-uniform loads), compile-time scale constants ---
    // SC[t] = sqrt(exp(-t/4) / (2 * sum_{j<8} exp(-j/4)))
    const float SC[LL] = {
        0.35764586f, 0.31562136f, 0.27853487f, 0.24580616f,
        0.21692316f, 0.19143401f, 0.16893992f, 0.14908896f };
    float2 cof[LL];
    #pragma unroll
    for (int t = 0; t < LL; ++t) {
        float2 u = cb[t];
        cof[t] = make_float2(SC[t] * u.x, SC[t] * u.y);
    }

    // --- twiddles from ONE sincos: w = exp(-2*pi*i*lane/64) ---
    float sn, cs;
    __sincosf(-0.0981747704246810387f * (float)lane, &sn, &cs);
    const float2 w1 = make_float2(cs, sn);
    const float2 w2 = cmul(w1, w1);
    const float2 w4 = cmul(w2, w2);
    const float2 w8 = cmul(w4, w4);
    const float2 ONE = make_float2(1.0f, 0.0f);

    // tw[s] = up ? w^(32>>s) : 1   (true twiddle = -w^(32>>s); sign folded into sgn
    //  applied to the shuffled operand).  tw[0] also carries NOISE_SCALE.
    //  w^32 = (-1)^lane -> tw0_up = -1;  w^16 = (-i)^lane -> {-1, i} on up lanes.
    float2 tw[6];
    float  sgn[6];
    tw[0] = make_float2((lane & 1) ? -NOISE_SCALE : NOISE_SCALE, 0.0f);
    tw[1] = (lane & 2) ? ((lane & 1) ? make_float2(0.0f, 1.0f)
                                     : make_float2(-1.0f, 0.0f)) : ONE;
    tw[2] = (lane & 4)  ? w8 : ONE;
    tw[3] = (lane & 8)  ? w4 : ONE;
    tw[4] = (lane & 16) ? w2 : ONE;
    tw[5] = hi          ? w1 : ONE;
    #pragma unroll
    for (int s = 0; s < 6; ++s) sgn[s] = (lane & (1 << s)) ? 1.0f : -1.0f;

    // --- H64[lane] = sum_{l<8} cof[l] * w^l via Horner (reuses w1) ---
    float2 H = cof[LL - 1];
    #pragma unroll
    for (int l = LL - 2; l >= 0; --l) {
        float2 Hw = cmul(H, w1);
        H = make_float2(Hw.x + cof[l].x, Hw.y + cof[l].y);
    }

    const size_t ob  = (size_t)b * MM;
    const size_t osb = (size_t)b * (SS * MM);

    if (wid == 1) out_H[ob + lane] = H;   // natural order, coalesced

    if (wid == 0) {
        // symbols 0 (pilot), 4, 8, 12
        float2 nv[4];
        nv[0] = nb[ 0*MKK + KK + rb];
        nv[1] = nb[ 4*MKK + KK + rb];
        nv[2] = nb[ 8*MKK + KK + rb];
        nv[3] = nb[12*MKK + KK + rb];
        float2 pv = pb[lane];
        float2 X1 = xb[ 3*MM + lane];
        float2 X2 = xb[ 7*MM + lane];
        float2 X3 = xb[11*MM + lane];
        fft64_dit<4>(nv, tw, sgn);    // NOISE_SCALE folded into tw[0]

        float ssq = pv.x * pv.x + pv.y * pv.y;
        ssq += xsh<0>(ssq);
        ssq += xsh<1>(ssq);
        ssq += xsh<2>(ssq);
        ssq += xsh<3>(ssq);
        ssq += xsh<4>(ssq);
        float2 sboth = swap32(ssq);
        ssq = sboth.x + sboth.y;
        float alpha = sqrtf(64.0f / ssq);   // sqrt(PWR/2)/sqrt(mean(pilot_raw^2))
        float2 X0 = make_float2(alpha * pv.x, alpha * pv.y);

        float2 o0 = cmul(H, X0), o1 = cmul(H, X1), o2 = cmul(H, X2), o3 = cmul(H, X3);
        out_pilot[ob + lane]          = make_float2(o0.x + nv[0].x, o0.y + nv[0].y);
        out_sig[osb +  3*MM + lane]   = make_float2(o1.x + nv[1].x, o1.y + nv[1].y);
        out_sig[osb +  7*MM + lane]   = make_float2(o2.x + nv[2].x, o2.y + nv[2].y);
        out_sig[osb + 11*MM + lane]   = make_float2(o3.x + nv[3].x, o3.y + nv[3].y);
    } else {
        // symbols wid, wid+4, wid+8  (payload indices wid-1, wid+3, wid+7)
        float2 nv[3];
        nv[0] = nb[(wid    ) * MKK + KK + rb];
        nv[1] = nb[(wid + 4) * MKK + KK + rb];
        nv[2] = nb[(wid + 8) * MKK + KK + rb];
        float2 X0 = xb[(wid - 1) * MM + lane];
        float2 X1 = xb[(wid + 3) * MM + lane];
        float2 X2 = xb[(wid + 7) * MM + lane];
        fft64_dit<3>(nv, tw, sgn);    // NOISE_SCALE folded into tw[0]

        float2 o0 = cmul(H, X0), o1 = cmul(H, X1), o2 = cmul(H, X2);
        out_sig[osb + (wid - 1) * MM + lane] = make_float2(o0.x + nv[0].x, o0.y + nv[0].y);
        out_sig[osb + (wid + 3) * MM + lane] = make_float2(o1.x + nv[1].x, o1.y + nv[1].y);
        out_sig[osb + (wid + 7) * MM + lane] = make_float2(o2.x + nv[2].x, o2.y + nv[2].y);
    }

    if (b == 0 && tid == 0) out_scalar[0] = NOISE_PWR;
}

extern "C" void kernel_launch(void* const* d_in, const int* in_sizes, int n_in,
                              void* d_out, int out_size, void* d_ws, size_t ws_size,
                              hipStream_t stream) {
    const float2* x  = (const float2*)d_in[0];
    const float2* pr = (const float2*)d_in[1];
    const float2* cu = (const float2*)d_in[2];
    const float2* nu = (const float2*)d_in[3];

    float* out = (float*)d_out;
    float2* out_pilot = (float2*)(out + OFF_PILOT);
    float2* out_sig   = (float2*)(out + OFF_SIG);
    float2* out_H     = (float2*)(out + OFF_H);
    float*  out_sc    = out + OFF_SCALAR;

    ofdm_kernel<<<dim3(NN*PP), dim3(256), 0, stream>>>(
        x, pr, cu, nu, out_pilot, out_sig, out_H, out_sc);
}